// Round 2
// baseline (991.800 us; speedup 1.0000x reference)
//
#include <hip/hip_runtime.h>

constexpr int H    = 128;
constexpr int NN   = 10000;
constexpr int EE   = 160000;
constexpr int RCN  = 4;      // R*C
constexpr int NG   = 64;     // graphs per replica
constexpr int OUTF = 64;
constexpr int DSEG = 256;    // RCN*NG

__device__ __forceinline__ float gelu_f(float x){
  return 0.5f*x*(1.0f + erff(x*0.70710678118654752440f));
}

// ---------- edge mask: em4[e] = {nm[rc][src]*nm[rc][dst]}_{rc=0..3}
__global__ void k_edge_mask(const int* __restrict__ src, const int* __restrict__ dst,
                            const float* __restrict__ nm, float4* __restrict__ em4){
  int e = blockIdx.x*256 + threadIdx.x;
  if(e >= EE) return;
  int s = src[e], d = dst[e];
  float4 m;
  m.x = nm[0*NN+s]*nm[0*NN+d];
  m.y = nm[1*NN+s]*nm[1*NN+d];
  m.z = nm[2*NN+s]*nm[2*NN+d];
  m.w = nm[3*NN+s]*nm[3*NN+d];
  em4[e] = m;
}

// ---------- CSR build
__global__ void k_hist(const int* __restrict__ dst, int* __restrict__ cnt){
  int e = blockIdx.x*256 + threadIdx.x;
  if(e < EE) atomicAdd(&cnt[dst[e]], 1);
}

__global__ __launch_bounds__(1024) void k_scan(const int* __restrict__ cnt,
                                               int* __restrict__ rs, int* __restrict__ cur){
  __shared__ int part[1024];
  int t = threadIdx.x;
  const int CH = 10;           // 1024*10 >= NN
  int base = t*CH;
  int s = 0;
  #pragma unroll
  for(int j=0;j<CH;j++){ int i = base+j; if(i<NN) s += cnt[i]; }
  part[t] = s;
  __syncthreads();
  for(int off=1; off<1024; off<<=1){
    int v = (t>=off) ? part[t-off] : 0;
    __syncthreads();
    part[t] += v;
    __syncthreads();
  }
  int run = (t==0) ? 0 : part[t-1];
  #pragma unroll
  for(int j=0;j<CH;j++){
    int i = base+j;
    if(i<NN){ rs[i] = run; cur[i] = run; run += cnt[i]; }
  }
  if(t == 1023) rs[NN] = part[1023];
}

__global__ void k_fill(const int* __restrict__ dst,
                       int* __restrict__ cur, int* __restrict__ eid){
  int e = blockIdx.x*256 + threadIdx.x;
  if(e >= EE) return;
  int p = atomicAdd(&cur[dst[e]], 1);
  eid[p] = e;
}

// sort each node's edge list ascending (determinism) and produce esrc
__global__ void k_sortcsr(const int* __restrict__ rs, int* __restrict__ eid,
                          const int* __restrict__ src, int* __restrict__ esrc){
  int n = blockIdx.x*256 + threadIdx.x;
  if(n >= NN) return;
  int jb = rs[n], je = rs[n+1];
  for(int j=jb+1; j<je; j++){
    int v = eid[j];
    int k = j-1;
    while(k >= jb && eid[k] > v){ eid[k+1] = eid[k]; k--; }
    eid[k+1] = v;
  }
  for(int j=jb; j<je; j++) esrc[j] = src[eid[j]];
}

// graph boundaries: batch is sorted; gs[g] = first n with batch[n] >= g, gs[NG]=NN
__global__ void k_gbounds(const int* __restrict__ batch, int* __restrict__ gs){
  int g = threadIdx.x;
  if(g > NG) return;
  if(g == NG){ gs[NG] = NN; return; }
  int lo = 0, hi = NN;
  while(lo < hi){
    int mid = (lo+hi)>>1;
    if(batch[mid] < g) lo = mid+1; else hi = mid;
  }
  gs[g] = lo;
}

// ---------- emb = edge_attr @ W + b   (EE x H) x (H x H), 128-row tiles
__global__ __launch_bounds__(512) void k_emb(const float* __restrict__ A, const float* __restrict__ W,
                       const float* __restrict__ bias, float* __restrict__ emb){
  __shared__ float Wl[H*H];      // 64 KB
  __shared__ float Al[128*H];    // 64 KB
  int t = threadIdx.x;
  {
    const float4* w4 = (const float4*)W; float4* wl = (float4*)Wl;
    #pragma unroll
    for(int i=0;i<8;i++) wl[t+i*512] = w4[t+i*512];
    const float4* a4 = (const float4*)(A + (size_t)blockIdx.x*128*H);
    float4* al = (float4*)Al;
    #pragma unroll
    for(int i=0;i<8;i++) al[t+i*512] = a4[t+i*512];
  }
  __syncthreads();
  int tx = t & 31, ty = t >> 5;
  int c0 = tx*4, r0 = ty*8;
  float acc[8][4];
  #pragma unroll
  for(int i=0;i<8;i++){ acc[i][0]=0.f; acc[i][1]=0.f; acc[i][2]=0.f; acc[i][3]=0.f; }
  for(int k=0;k<H;k+=4){
    float4 w0 = *(const float4*)&Wl[(k+0)*H+c0];
    float4 w1 = *(const float4*)&Wl[(k+1)*H+c0];
    float4 w2 = *(const float4*)&Wl[(k+2)*H+c0];
    float4 w3 = *(const float4*)&Wl[(k+3)*H+c0];
    #pragma unroll
    for(int i=0;i<8;i++){
      float4 a = *(const float4*)&Al[(r0+i)*H+k];
      acc[i][0] += a.x*w0.x + a.y*w1.x + a.z*w2.x + a.w*w3.x;
      acc[i][1] += a.x*w0.y + a.y*w1.y + a.z*w2.y + a.w*w3.y;
      acc[i][2] += a.x*w0.z + a.y*w1.z + a.z*w2.z + a.w*w3.z;
      acc[i][3] += a.x*w0.w + a.y*w1.w + a.z*w2.w + a.w*w3.w;
    }
  }
  float4 bv = *(const float4*)&bias[c0];
  float* ob = emb + (size_t)blockIdx.x*128*H;
  #pragma unroll
  for(int i=0;i<8;i++){
    float4 o;
    o.x = acc[i][0]+bv.x; o.y = acc[i][1]+bv.y;
    o.z = acc[i][2]+bv.z; o.w = acc[i][3]+bv.w;
    *(float4*)&ob[(r0+i)*H + c0] = o;
  }
}

// ---------- aggregation: t[rc][n] = (1+eps)*h[rc][n] + sum_e gelu(h[rc][src]+emb[e])*mask[rc][e]
template<bool FIRST>
__global__ __launch_bounds__(256) void k_agg(const float* __restrict__ hin, const float* __restrict__ emb,
                       const float4* __restrict__ em4, const int* __restrict__ rs,
                       const int* __restrict__ eid, const int* __restrict__ esrc,
                       const float* __restrict__ epsp, float* __restrict__ tout){
  int t = threadIdx.x;
  int lane = t & 31, g = t >> 5;
  int n = blockIdx.x*8 + g;
  int d0 = lane*4;
  float4 acc[RCN];
  #pragma unroll
  for(int rc=0;rc<RCN;rc++){ acc[rc].x=0.f; acc[rc].y=0.f; acc[rc].z=0.f; acc[rc].w=0.f; }
  int jb = rs[n], je = rs[n+1];
  for(int j=jb; j<je; j++){
    int e = eid[j], s = esrc[j];
    float4 ev = *(const float4*)&emb[(size_t)e*H + d0];
    float4 m  = em4[e];
    float ms[RCN] = {m.x, m.y, m.z, m.w};
    if(FIRST){
      float4 xv = *(const float4*)&hin[(size_t)s*H + d0];
      float gx = gelu_f(xv.x+ev.x);
      float gy = gelu_f(xv.y+ev.y);
      float gz = gelu_f(xv.z+ev.z);
      float gw = gelu_f(xv.w+ev.w);
      #pragma unroll
      for(int rc=0;rc<RCN;rc++){
        acc[rc].x += gx*ms[rc]; acc[rc].y += gy*ms[rc];
        acc[rc].z += gz*ms[rc]; acc[rc].w += gw*ms[rc];
      }
    } else {
      #pragma unroll
      for(int rc=0;rc<RCN;rc++){
        float4 hv = *(const float4*)&hin[((size_t)rc*NN + s)*H + d0];
        acc[rc].x += gelu_f(hv.x+ev.x)*ms[rc];
        acc[rc].y += gelu_f(hv.y+ev.y)*ms[rc];
        acc[rc].z += gelu_f(hv.z+ev.z)*ms[rc];
        acc[rc].w += gelu_f(hv.w+ev.w)*ms[rc];
      }
    }
  }
  float e1 = 1.0f + epsp[0];
  #pragma unroll
  for(int rc=0;rc<RCN;rc++){
    const float* hb = FIRST ? (hin + (size_t)n*H) : (hin + ((size_t)rc*NN + n)*H);
    float4 hv = *(const float4*)&hb[d0];
    float4 o;
    o.x = e1*hv.x + acc[rc].x;
    o.y = e1*hv.y + acc[rc].y;
    o.z = e1*hv.z + acc[rc].z;
    o.w = e1*hv.w + acc[rc].w;
    *(float4*)&tout[((size_t)rc*NN + n)*H + d0] = o;
  }
}

// ---------- conv: h = gelu(gelu(t@W1+b1)@W2+b2), 32-row tiles, W1+W2 in LDS
__global__ __launch_bounds__(512) void k_conv(const float* __restrict__ T, const float* __restrict__ W1,
                        const float* __restrict__ b1, const float* __restrict__ W2,
                        const float* __restrict__ b2, float* __restrict__ Ho){
  __shared__ float W1l[H*H];   // 64 KB
  __shared__ float W2l[H*H];   // 64 KB
  __shared__ float Tl[32*H];   // 16 KB  (reused for u)
  int t = threadIdx.x;
  {
    const float4* w4 = (const float4*)W1; float4* wl = (float4*)W1l;
    #pragma unroll
    for(int i=0;i<8;i++) wl[t+i*512] = w4[t+i*512];
    const float4* v4 = (const float4*)W2; float4* vl = (float4*)W2l;
    #pragma unroll
    for(int i=0;i<8;i++) vl[t+i*512] = v4[t+i*512];
    const float4* t4 = (const float4*)(T + (size_t)blockIdx.x*32*H);
    float4* tl = (float4*)Tl;
    tl[t] = t4[t];
    tl[t+512] = t4[t+512];
  }
  __syncthreads();
  int tx = t & 31, ty = t >> 5;
  int c0 = tx*4, r0 = ty*2;
  float acc[2][4];
  #pragma unroll
  for(int i=0;i<2;i++){ acc[i][0]=0.f; acc[i][1]=0.f; acc[i][2]=0.f; acc[i][3]=0.f; }
  for(int k=0;k<H;k+=4){
    float4 w0 = *(const float4*)&W1l[(k+0)*H+c0];
    float4 w1 = *(const float4*)&W1l[(k+1)*H+c0];
    float4 w2 = *(const float4*)&W1l[(k+2)*H+c0];
    float4 w3 = *(const float4*)&W1l[(k+3)*H+c0];
    #pragma unroll
    for(int i=0;i<2;i++){
      float4 a = *(const float4*)&Tl[(r0+i)*H+k];
      acc[i][0] += a.x*w0.x + a.y*w1.x + a.z*w2.x + a.w*w3.x;
      acc[i][1] += a.x*w0.y + a.y*w1.y + a.z*w2.y + a.w*w3.y;
      acc[i][2] += a.x*w0.z + a.y*w1.z + a.z*w2.z + a.w*w3.z;
      acc[i][3] += a.x*w0.w + a.y*w1.w + a.z*w2.w + a.w*w3.w;
    }
  }
  float4 bv = *(const float4*)&b1[c0];
  float u[2][4];
  #pragma unroll
  for(int i=0;i<2;i++){
    u[i][0] = gelu_f(acc[i][0]+bv.x);
    u[i][1] = gelu_f(acc[i][1]+bv.y);
    u[i][2] = gelu_f(acc[i][2]+bv.z);
    u[i][3] = gelu_f(acc[i][3]+bv.w);
  }
  __syncthreads();
  #pragma unroll
  for(int i=0;i<2;i++){
    float4 uv; uv.x=u[i][0]; uv.y=u[i][1]; uv.z=u[i][2]; uv.w=u[i][3];
    *(float4*)&Tl[(r0+i)*H+c0] = uv;
  }
  __syncthreads();
  #pragma unroll
  for(int i=0;i<2;i++){ acc[i][0]=0.f; acc[i][1]=0.f; acc[i][2]=0.f; acc[i][3]=0.f; }
  for(int k=0;k<H;k+=4){
    float4 w0 = *(const float4*)&W2l[(k+0)*H+c0];
    float4 w1 = *(const float4*)&W2l[(k+1)*H+c0];
    float4 w2 = *(const float4*)&W2l[(k+2)*H+c0];
    float4 w3 = *(const float4*)&W2l[(k+3)*H+c0];
    #pragma unroll
    for(int i=0;i<2;i++){
      float4 a = *(const float4*)&Tl[(r0+i)*H+k];
      acc[i][0] += a.x*w0.x + a.y*w1.x + a.z*w2.x + a.w*w3.x;
      acc[i][1] += a.x*w0.y + a.y*w1.y + a.z*w2.y + a.w*w3.y;
      acc[i][2] += a.x*w0.z + a.y*w1.z + a.z*w2.z + a.w*w3.z;
      acc[i][3] += a.x*w0.w + a.y*w1.w + a.z*w2.w + a.w*w3.w;
    }
  }
  float4 b2v = *(const float4*)&b2[c0];
  float* ob = Ho + (size_t)blockIdx.x*32*H;
  #pragma unroll
  for(int i=0;i<2;i++){
    float4 o;
    o.x = gelu_f(acc[i][0]+b2v.x);
    o.y = gelu_f(acc[i][1]+b2v.y);
    o.z = gelu_f(acc[i][2]+b2v.z);
    o.w = gelu_f(acc[i][3]+b2v.w);
    *(float4*)&ob[(r0+i)*H + c0] = o;
  }
}

// ---------- final MLP: y = gelu(h@W1+b1)@W2+b2  (no pooling here; deterministic)
__global__ __launch_bounds__(512) void k_mlp(const float* __restrict__ Hf, const float* __restrict__ W1,
     const float* __restrict__ b1, const float* __restrict__ W2, const float* __restrict__ b2,
     float* __restrict__ y){
  __shared__ float W1l[H*H];     // 64 KB
  __shared__ float W2l[H*OUTF];  // 32 KB
  __shared__ float Tl[32*H];     // 16 KB
  int t = threadIdx.x;
  {
    const float4* w4 = (const float4*)W1; float4* wl = (float4*)W1l;
    #pragma unroll
    for(int i=0;i<8;i++) wl[t+i*512] = w4[t+i*512];
    const float4* v4 = (const float4*)W2; float4* vl = (float4*)W2l;
    #pragma unroll
    for(int i=0;i<4;i++) vl[t+i*512] = v4[t+i*512];
    const float4* t4 = (const float4*)(Hf + (size_t)blockIdx.x*32*H);
    float4* tl = (float4*)Tl;
    tl[t] = t4[t];
    tl[t+512] = t4[t+512];
  }
  __syncthreads();
  {
    int tx = t & 31, ty = t >> 5;
    int c0 = tx*4, r0 = ty*2;
    float acc[2][4];
    #pragma unroll
    for(int i=0;i<2;i++){ acc[i][0]=0.f; acc[i][1]=0.f; acc[i][2]=0.f; acc[i][3]=0.f; }
    for(int k=0;k<H;k+=4){
      float4 w0 = *(const float4*)&W1l[(k+0)*H+c0];
      float4 w1 = *(const float4*)&W1l[(k+1)*H+c0];
      float4 w2 = *(const float4*)&W1l[(k+2)*H+c0];
      float4 w3 = *(const float4*)&W1l[(k+3)*H+c0];
      #pragma unroll
      for(int i=0;i<2;i++){
        float4 a = *(const float4*)&Tl[(r0+i)*H+k];
        acc[i][0] += a.x*w0.x + a.y*w1.x + a.z*w2.x + a.w*w3.x;
        acc[i][1] += a.x*w0.y + a.y*w1.y + a.z*w2.y + a.w*w3.y;
        acc[i][2] += a.x*w0.z + a.y*w1.z + a.z*w2.z + a.w*w3.z;
        acc[i][3] += a.x*w0.w + a.y*w1.w + a.z*w2.w + a.w*w3.w;
      }
    }
    float4 bv = *(const float4*)&b1[c0];
    float u[2][4];
    #pragma unroll
    for(int i=0;i<2;i++){
      u[i][0] = gelu_f(acc[i][0]+bv.x);
      u[i][1] = gelu_f(acc[i][1]+bv.y);
      u[i][2] = gelu_f(acc[i][2]+bv.z);
      u[i][3] = gelu_f(acc[i][3]+bv.w);
    }
    __syncthreads();
    #pragma unroll
    for(int i=0;i<2;i++){
      float4 uv; uv.x=u[i][0]; uv.y=u[i][1]; uv.z=u[i][2]; uv.w=u[i][3];
      *(float4*)&Tl[(r0+i)*H+c0] = uv;
    }
  }
  __syncthreads();
  // GEMM2: 32 rows x 64 cols; thread = (row = t>>4, 4 cols at (t&15)*4)
  int tx2 = t & 15, ty2 = t >> 4;
  int c2 = tx2*4;
  float a0=0.f, a1=0.f, a2=0.f, a3=0.f;
  for(int k=0;k<H;k+=4){
    float4 w0 = *(const float4*)&W2l[(k+0)*OUTF + c2];
    float4 w1 = *(const float4*)&W2l[(k+1)*OUTF + c2];
    float4 w2 = *(const float4*)&W2l[(k+2)*OUTF + c2];
    float4 w3 = *(const float4*)&W2l[(k+3)*OUTF + c2];
    float4 a = *(const float4*)&Tl[ty2*H + k];
    a0 += a.x*w0.x + a.y*w1.x + a.z*w2.x + a.w*w3.x;
    a1 += a.x*w0.y + a.y*w1.y + a.z*w2.y + a.w*w3.y;
    a2 += a.x*w0.z + a.y*w1.z + a.z*w2.z + a.w*w3.z;
    a3 += a.x*w0.w + a.y*w1.w + a.z*w2.w + a.w*w3.w;
  }
  int grow = blockIdx.x*32 + ty2;
  float4 o;
  o.x = a0 + b2[c2+0];
  o.y = a1 + b2[c2+1];
  o.z = a2 + b2[c2+2];
  o.w = a3 + b2[c2+3];
  *(float4*)&y[(size_t)grow*OUTF + c2] = o;
}

// ---------- deterministic masked segment mean over contiguous node ranges
__global__ __launch_bounds__(64) void k_pool(const float* __restrict__ y, const float* __restrict__ nm,
                       const int* __restrict__ gs, float* __restrict__ out){
  int seg = blockIdx.x;          // 0..DSEG-1
  int rc = seg / NG;
  int g  = seg - rc*NG;
  int c  = threadIdx.x;          // 0..63
  int nb = gs[g], ne = gs[g+1];
  float num = 0.f, den = 0.f;
  for(int n=nb; n<ne; n++){
    float w = nm[rc*NN + n];
    num += y[((size_t)rc*NN + n)*OUTF + c] * w;
    den += w;
  }
  out[seg*OUTF + c] = num / fmaxf(den, 1e-12f);
}

extern "C" void kernel_launch(void* const* d_in, const int* in_sizes, int n_in,
                              void* d_out, int out_size, void* d_ws, size_t ws_size,
                              hipStream_t stream){
  const float* x         = (const float*)d_in[0];
  const float* edge_attr = (const float*)d_in[1];
  const float* node_mask = (const float*)d_in[2];
  const float* bond_W    = (const float*)d_in[3];
  const float* bond_b    = (const float*)d_in[4];
  const float* epsv      = (const float*)d_in[5];
  const float* conv_W1   = (const float*)d_in[6];
  const float* conv_b1   = (const float*)d_in[7];
  const float* conv_W2   = (const float*)d_in[8];
  const float* conv_b2   = (const float*)d_in[9];
  const float* mlp_W1    = (const float*)d_in[10];
  const float* mlp_b1    = (const float*)d_in[11];
  const float* mlp_W2    = (const float*)d_in[12];
  const float* mlp_b2    = (const float*)d_in[13];
  const int*   eidx      = (const int*)d_in[14];
  const int*   batch     = (const int*)d_in[15];
  const int* srcp = eidx;
  const int* dstp = eidx + EE;

  char* p = (char*)d_ws;
  auto alloc = [&](size_t bytes)->char*{
    char* r = p; p += (bytes + 255) & ~size_t(255); return r;
  };
  float*  h    = (float*) alloc((size_t)RCN*NN*H*4);
  float*  tbuf = (float*) alloc((size_t)RCN*NN*H*4);
  float*  emb  = (float*) alloc((size_t)EE*H*4);
  float4* em4  = (float4*)alloc((size_t)EE*16);
  float*  y    = (float*) alloc((size_t)RCN*NN*OUTF*4);
  int*    cnt  = (int*)   alloc((size_t)NN*4);
  int*    rs   = (int*)   alloc((size_t)(NN+1)*4);
  int*    cur  = (int*)   alloc((size_t)NN*4);
  int*    eid  = (int*)   alloc((size_t)EE*4);
  int*    esrc = (int*)   alloc((size_t)EE*4);
  int*    gs   = (int*)   alloc((size_t)(NG+1)*4);
  if((size_t)(p - (char*)d_ws) > ws_size) return;  // insufficient workspace

  hipMemsetAsync(cnt, 0, (size_t)NN*4, stream);

  k_edge_mask<<<(EE+255)/256, 256, 0, stream>>>(srcp, dstp, node_mask, em4);
  k_hist     <<<(EE+255)/256, 256, 0, stream>>>(dstp, cnt);
  k_scan     <<<1, 1024, 0, stream>>>(cnt, rs, cur);
  k_fill     <<<(EE+255)/256, 256, 0, stream>>>(dstp, cur, eid);
  k_sortcsr  <<<(NN+255)/256, 256, 0, stream>>>(rs, eid, srcp, esrc);
  k_gbounds  <<<1, 128, 0, stream>>>(batch, gs);

  for(int l=0; l<3; l++){
    k_emb<<<EE/128, 512, 0, stream>>>(edge_attr, bond_W + (size_t)l*H*H, bond_b + l*H, emb);
    if(l == 0)
      k_agg<true ><<<NN/8, 256, 0, stream>>>(x, emb, em4, rs, eid, esrc, epsv + l, tbuf);
    else
      k_agg<false><<<NN/8, 256, 0, stream>>>(h, emb, em4, rs, eid, esrc, epsv + l, tbuf);
    k_conv<<<RCN*NN/32, 512, 0, stream>>>(tbuf, conv_W1 + (size_t)l*H*H, conv_b1 + l*H,
                                          conv_W2 + (size_t)l*H*H, conv_b2 + l*H, h);
  }
  k_mlp<<<RCN*NN/32, 512, 0, stream>>>(h, mlp_W1, mlp_b1, mlp_W2, mlp_b2, y);
  k_pool<<<DSEG, 64, 0, stream>>>(y, node_mask, gs, (float*)d_out);
}